// Round 2
// baseline (960.102 us; speedup 1.0000x reference)
//
#include <hip/hip_runtime.h>
#include <math.h>

// Problem constants
#define N_TOK   16384
#define N_E     16384
#define CDIM    256
#define NCH     8
#define CHSZ    (N_E / NCH)      // 2048 codes per chunk
#define L2E100  144.26950408889634f   // 100 * log2(e)
#define DELTA_C 0.06f            // candidate window below running row max
#define EPS_NT  0.008f           // near-tie window for fp64 argmin re-rank
#define CAP_BLK 1536u            // per-block candidate cap (proven r6-r14)
#define NT_CAP  65536u

typedef __attribute__((ext_vector_type(8))) short short8;
typedef __attribute__((ext_vector_type(4))) float f32x4;

// ---- workspace layout (float offsets); base 42.5 MB, zT optional tail ----
#define OFF_A2   0u          // ushort[16384*256] bf16-hi normalized z (token-major)
#define OFF_B2   2097152u    // ushort[16384*256] bf16-hi normalized emb
#define OFF_RMX  4194304u    // 16384 u32 ordered-key row max
#define OFF_CS   4210688u    // 16384 colsum
#define OFF_SC   4227072u    // 16 scalars
#define OFF_RK   4227088u    // 16384 u64 rowkey (8B aligned)
#define OFF_NT   4259856u    // 65536 u32 near-tie list
#define OFF_NTC  4325392u    // 16
#define OFF_CBC  4325408u    // 2048 per-block counts
#define OFF_IDX  4327456u    // 16384 int
#define OFF_CAND 4343840u    // u64[2048*1536] {f32 t | row<<14|col} (8B aligned)
#define OFF_ZT   10635296u   // float[16384*256] raw z token-major (refine coalescing)
#define NEED_ZT_BYTES 59318400ull

__device__ __forceinline__ unsigned short f2bf(float x) {
  unsigned u = __float_as_uint(x);
  unsigned r = (u + 0x7fffu + ((u >> 16) & 1u)) >> 16;
  return (unsigned short)r;
}
__device__ __forceinline__ float bf2f(unsigned short h) {
  return __uint_as_float(((unsigned)h) << 16);
}
__device__ __forceinline__ unsigned fkey(float f) {      // order-preserving float->uint
  unsigned u = __float_as_uint(f);
  return (u & 0x80000000u) ? ~u : (u | 0x80000000u);
}
__device__ __forceinline__ float keyf(unsigned k) {
  return (k & 0x80000000u) ? __uint_as_float(k ^ 0x80000000u) : __uint_as_float(~k);
}

__device__ __forceinline__ void async_load16(const void* g, void* l) {
  __builtin_amdgcn_global_load_lds((const __attribute__((address_space(1))) void*)g,
                                   (__attribute__((address_space(3))) void*)l, 16, 0, 0);
}

__device__ __forceinline__ float blockReduceSum256(float v, float* sbuf) {
  __syncthreads();
  v += __shfl_down(v, 32);
  v += __shfl_down(v, 16);
  v += __shfl_down(v, 8);
  v += __shfl_down(v, 4);
  v += __shfl_down(v, 2);
  v += __shfl_down(v, 1);
  const int tid = threadIdx.x;
  if ((tid & 63) == 0) sbuf[tid >> 6] = v;
  __syncthreads();
  return sbuf[0] + sbuf[1] + sbuf[2] + sbuf[3];
}

// ---------- emb normalize (wave-per-row) + fused workspace zeroing ----------
__global__ __launch_bounds__(256) void k_norm_emb(const float* __restrict__ emb,
    unsigned short* __restrict__ B2, float* __restrict__ colsum,
    float* __restrict__ scalars, unsigned long long* __restrict__ rowkey,
    unsigned* __restrict__ ntc, unsigned* __restrict__ rowMaxU) {
  const int tid = threadIdx.x, lane = tid & 63, wv = tid >> 6;
  if (blockIdx.x < 64) {
    const int i = blockIdx.x * 256 + tid;
    colsum[i] = 0.f;
    rowkey[i] = ~0ull;
    rowMaxU[i] = 0u;
    if (i < 16) { scalars[i] = 0.f; ntc[i] = 0u; }
  }
  const int k = blockIdx.x * 4 + wv;
  const float4 v = *(const float4*)&emb[(size_t)k * CDIM + lane * 4];
  float ss = v.x * v.x + v.y * v.y + v.z * v.z + v.w * v.w;
#pragma unroll
  for (int off = 1; off < 64; off <<= 1) ss += __shfl_xor(ss, off);
  const float r = 1.0f / fmaxf(sqrtf(ss), 1e-12f);
  ushort4 o;
  o.x = f2bf(v.x * r); o.y = f2bf(v.y * r);
  o.z = f2bf(v.z * r); o.w = f2bf(v.w * r);
  *(ushort4*)&B2[(size_t)k * CDIM + lane * 4] = o;
}

// ---------- coalesced z normalize + optional raw token-major copy ----------
__global__ __launch_bounds__(256) void k_norm_z(const float* __restrict__ z,
                                                unsigned short* __restrict__ A2,
                                                float* __restrict__ zT) {
  __shared__ float ssb[4][64];
  __shared__ float rn[64];
  __shared__ unsigned short tile[64 * 264];
  __shared__ float tileF[64 * 260];
  const int b = blockIdx.x >> 4, hw0 = (blockIdx.x & 15) * 64;
  const int tid = threadIdx.x, cg = tid >> 6, hwl = tid & 63;
  float ss = 0.f;
#pragma unroll 8
  for (int i = 0; i < 64; ++i) {
    const int c = cg + i * 4;
    const float x = z[((size_t)(b * CDIM + c) << 10) + hw0 + hwl];
    ss = fmaf(x, x, ss);
  }
  ssb[cg][hwl] = ss;
  __syncthreads();
  if (tid < 64) {
    const float t = ssb[0][tid] + ssb[1][tid] + ssb[2][tid] + ssb[3][tid];
    rn[tid] = 1.0f / fmaxf(sqrtf(t), 1e-12f);
  }
  __syncthreads();
  const float r = rn[hwl];
#pragma unroll 8
  for (int i = 0; i < 64; ++i) {
    const int c = cg + i * 4;
    const float x = z[((size_t)(b * CDIM + c) << 10) + hw0 + hwl];
    tile[hwl * 264 + c] = f2bf(x * r);
    tileF[hwl * 260 + c] = x;
  }
  __syncthreads();
  const int rr = tid >> 5, tt = tid & 31;
#pragma unroll
  for (int it = 0; it < 8; ++it) {
    const int row = rr + 8 * it;
    const int token = b * 1024 + hw0 + row;
    const uint4 v = *(const uint4*)&tile[row * 264 + tt * 8];
    *(uint4*)&A2[(size_t)token * CDIM + tt * 8] = v;
    if (zT != nullptr) {
      const float4 f0 = *(const float4*)&tileF[row * 260 + tt * 4];
      const float4 f1 = *(const float4*)&tileF[row * 260 + 128 + tt * 4];
      *(float4*)&zT[(size_t)token * CDIM + tt * 4] = f0;
      *(float4*)&zT[(size_t)token * CDIM + 128 + tt * 4] = f1;
    }
  }
}

// ============ pass 1: A in registers, B dbuf, pipelined epilogue (ct k overlapped
// with ct k+1's MFMA stages; EPI-A in st0, EPI-B in st1, piggybacking st barriers) ============
__global__ __launch_bounds__(256, 3) void k_pass1(const unsigned short* __restrict__ A2,
    const unsigned short* __restrict__ B2,
    unsigned long long* __restrict__ cand, unsigned* __restrict__ cbc,
    unsigned* __restrict__ rowMaxU) {
  __shared__ alignas(16) unsigned short Bt[2][128 * 64];  // 2 x 16 KB B dbuf
  __shared__ unsigned smaxU[64];
  __shared__ unsigned lcnt;
  const int rt = blockIdx.x, chunk = blockIdx.y;   // swizzle: co-resident blocks share chunk
  const int r0 = rt * 64, k0 = chunk * CHSZ;
  const int blin = rt * NCH + chunk;
  const int tid = threadIdx.x, lane = tid & 63, w = tid >> 6;
  const int wrr = (w & 1) * 32, wc = (w >> 1) * 64;
  const int l15 = lane & 15, quad = lane >> 4;

  if (tid == 0) lcnt = 0u;
  if (tid < 64) smaxU[tid] = 0u;

  // A fragments -> registers (rows fixed per wave for whole kernel).
  short8 afr[2][4][2];
#pragma unroll
  for (int ti = 0; ti < 2; ++ti) {
    const size_t rbase = (size_t)(r0 + wrr + ti * 16 + l15) * CDIM;
#pragma unroll
    for (int st = 0; st < 4; ++st)
#pragma unroll
      for (int kk = 0; kk < 2; ++kk)
        afr[ti][st][kk] = *(const short8*)&A2[rbase + st * 64 + (((kk << 2) | quad) * 8)];
  }

  // per-thread B staging base (swizzle: position cg holds global group cg^(row&7));
  // stride across the 4 per-thread loads is constant: +32 rows = +8192 ushorts / +4096 LDS bytes.
  const int row0 = tid >> 3, cg0 = tid & 7;
  const int gcg0 = cg0 ^ (row0 & 7);
  const unsigned short* bsrc0 = B2 + (size_t)(k0 + row0) * CDIM + gcg0 * 8;
  const unsigned bofs0 = (unsigned)tid * 16u;

#pragma unroll
  for (int i = 0; i < 4; ++i)
    async_load16(bsrc0 + i * 8192, (char*)Bt[0] + bofs0 + i * 4096);

  // hoisted B LDS read offsets
  int boff[4][2];
#pragma unroll
  for (int tj = 0; tj < 4; ++tj) {
    const int br = wc + tj * 16 + l15;
#pragma unroll
    for (int kk = 0; kk < 2; ++kk)
      boff[tj][kk] = br * 64 + ((((kk << 2) | quad) ^ (br & 7)) * 8);
  }
  __syncthreads();

  f32x4 accA[2][4], accB[2][4];
  size_t cbase = 0;   // running bsrc advance (in ushorts)

  // computeCt: compute aN for ctNew while running ct(ctNew-1)'s epilogue on aO.
  auto computeCt = [&](f32x4 (&aN)[2][4], f32x4 (&aO)[2][4], int ctNew, int doEpi) {
    const int kbOld = k0 + (ctNew - 1) * 128;
    const unsigned short* bs = bsrc0 + cbase;
#pragma unroll
    for (int ti = 0; ti < 2; ++ti)
#pragma unroll
      for (int tj = 0; tj < 4; ++tj) aN[ti][tj] = (f32x4){0.f, 0.f, 0.f, 0.f};

#pragma unroll
    for (int st = 0; st < 4; ++st) {
      if (!(ctNew == 15 && st == 3)) {
        const int noff = (st < 3) ? (st + 1) * 64 : 32768;
        char* dbuf = (char*)Bt[(st + 1) & 1];
#pragma unroll
        for (int i = 0; i < 4; ++i)
          async_load16(bs + i * 8192 + noff, dbuf + bofs0 + i * 4096);
      }
      const unsigned short* bp = Bt[st & 1];
      __builtin_amdgcn_s_setprio(1);
#pragma unroll
      for (int kk = 0; kk < 2; ++kk) {
        short8 bfr[4];
#pragma unroll
        for (int tj = 0; tj < 4; ++tj)
          bfr[tj] = *(const short8*)&bp[boff[tj][kk]];
#pragma unroll
        for (int ti = 0; ti < 2; ++ti)
#pragma unroll
          for (int tj = 0; tj < 4; ++tj)
            aN[ti][tj] = __builtin_amdgcn_mfma_f32_16x16x32_bf16(afr[ti][st][kk], bfr[tj],
                                                                 aN[ti][tj], 0, 0, 0);
      }
      __builtin_amdgcn_s_setprio(0);

      if (doEpi && st == 0) {
        // EPI-A (prev ct): t = 2*dot, per-row max over this ct's 128 cols, merge to LDS.
#pragma unroll
        for (int ti = 0; ti < 2; ++ti)
#pragma unroll
          for (int tj = 0; tj < 4; ++tj) {
            f32x4 a = aO[ti][tj];
#pragma unroll
            for (int r = 0; r < 4; ++r) a[r] = a[r] + a[r];
            aO[ti][tj] = a;
          }
#pragma unroll
        for (int ti = 0; ti < 2; ++ti)
#pragma unroll
          for (int r = 0; r < 4; ++r) {
            float mt = fmaxf(fmaxf(aO[ti][0][r], aO[ti][1][r]),
                             fmaxf(aO[ti][2][r], aO[ti][3][r]));
            mt = fmaxf(mt, __shfl_xor(mt, 1));
            mt = fmaxf(mt, __shfl_xor(mt, 2));
            mt = fmaxf(mt, __shfl_xor(mt, 4));
            mt = fmaxf(mt, __shfl_xor(mt, 8));
            if (l15 == 0) atomicMax(&smaxU[wrr + ti * 16 + quad * 4 + r], fkey(mt));
          }
        // st0-end barrier (below) publishes all waves' maxes before EPI-B reads them.
      }
      if (doEpi && st == 1) {
        // EPI-B (prev ct): threshold vs running block max (monotone -> always safe), emit.
#pragma unroll
        for (int ti = 0; ti < 2; ++ti)
#pragma unroll
          for (int r = 0; r < 4; ++r) {
            const int rowloc = wrr + ti * 16 + quad * 4 + r;
            const float thr = keyf(smaxU[rowloc]) - DELTA_C;
            const unsigned rowg = (unsigned)(r0 + rowloc);
#pragma unroll
            for (int tj = 0; tj < 4; ++tj) {
              const float t = aO[ti][tj][r];
              if (t >= thr) {
                const unsigned slot = atomicAdd(&lcnt, 1u);
                if (slot < CAP_BLK) {
                  const unsigned pr = (rowg << 14) | (unsigned)(kbOld + wc + tj * 16 + l15);
                  cand[(size_t)blin * CAP_BLK + slot] =
                      ((unsigned long long)__float_as_uint(t) << 32) | pr;
                }
              }
            }
          }
      }
      __syncthreads();
    }
    cbase += 32768;
  };

  computeCt(accA, accB, 0, 0);             // prologue: no epilogue yet
#pragma unroll 1
  for (int ctp = 0; ctp < 7; ++ctp) {
    computeCt(accB, accA, 2 * ctp + 1, 1); // compute odd ct, epilogue even ct
    computeCt(accA, accB, 2 * ctp + 2, 1); // compute even ct, epilogue odd ct
  }
  computeCt(accB, accA, 15, 1);            // compute ct15, epilogue ct14

  // ---- tail epilogue for ct15 (accB) ----
  {
    const int kb = k0 + 15 * 128;
#pragma unroll
    for (int ti = 0; ti < 2; ++ti)
#pragma unroll
      for (int tj = 0; tj < 4; ++tj) {
        f32x4 a = accB[ti][tj];
#pragma unroll
        for (int r = 0; r < 4; ++r) a[r] = a[r] + a[r];
        accB[ti][tj] = a;
      }
#pragma unroll
    for (int ti = 0; ti < 2; ++ti)
#pragma unroll
      for (int r = 0; r < 4; ++r) {
        float mt = fmaxf(fmaxf(accB[ti][0][r], accB[ti][1][r]),
                         fmaxf(accB[ti][2][r], accB[ti][3][r]));
        mt = fmaxf(mt, __shfl_xor(mt, 1));
        mt = fmaxf(mt, __shfl_xor(mt, 2));
        mt = fmaxf(mt, __shfl_xor(mt, 4));
        mt = fmaxf(mt, __shfl_xor(mt, 8));
        if (l15 == 0) atomicMax(&smaxU[wrr + ti * 16 + quad * 4 + r], fkey(mt));
      }
    __syncthreads();
#pragma unroll
    for (int ti = 0; ti < 2; ++ti)
#pragma unroll
      for (int r = 0; r < 4; ++r) {
        const int rowloc = wrr + ti * 16 + quad * 4 + r;
        const float thr = keyf(smaxU[rowloc]) - DELTA_C;
        const unsigned rowg = (unsigned)(r0 + rowloc);
#pragma unroll
        for (int tj = 0; tj < 4; ++tj) {
          const float t = accB[ti][tj][r];
          if (t >= thr) {
            const unsigned slot = atomicAdd(&lcnt, 1u);
            if (slot < CAP_BLK) {
              const unsigned pr = (rowg << 14) | (unsigned)(kb + wc + tj * 16 + l15);
              cand[(size_t)blin * CAP_BLK + slot] =
                  ((unsigned long long)__float_as_uint(t) << 32) | pr;
            }
          }
        }
      }
  }
  __syncthreads();
  if (tid < 64) atomicMax(&rowMaxU[r0 + tid], smaxU[tid]);
  if (tid == 0) cbc[blin] = lcnt < CAP_BLK ? lcnt : CAP_BLK;
}

// ---------- fused candidate processing: block = rt, LDS-local Z/E ----------
__global__ __launch_bounds__(256) void k_cstat2(const unsigned long long* __restrict__ cand,
    const unsigned* __restrict__ cbc, const unsigned* __restrict__ rowMaxU,
    float* __restrict__ colsum, unsigned* __restrict__ ntList,
    unsigned* __restrict__ ntc, float* __restrict__ scalars) {
  __shared__ float lM[64], lZ[64], lE[64], lIZ[64];
  __shared__ float sbuf[4];
  const int rt = blockIdx.x, r0 = rt * 64;
  const int tid = threadIdx.x, lane = tid & 63;
  if (tid < 64) {
    lM[tid] = keyf(rowMaxU[r0 + tid]);
    lZ[tid] = 0.f; lE[tid] = 0.f;
  }
  __syncthreads();
  for (int sub = 0; sub < NCH; ++sub) {
    const int blin = rt * NCH + sub;
    const unsigned cnt = cbc[blin] < CAP_BLK ? cbc[blin] : CAP_BLK;
    for (unsigned i = tid; i < cnt; i += 256u) {
      const unsigned long long e = cand[(size_t)blin * CAP_BLK + i];
      const unsigned pr = (unsigned)(e & 0xFFFFFFFu);
      const float t = __uint_as_float((unsigned)(e >> 32));
      const int rowl = (int)((pr >> 14) & 63u);
      const float d = t - lM[rowl];
      const float ex = exp2f(d * L2E100);
      atomicAdd(&lZ[rowl], ex);
      atomicAdd(&lE[rowl], d * 100.0f * ex);
    }
  }
  __syncthreads();
  float ent = 0.f;
  if (tid < 64) {
    const float Z = lZ[tid];
    lIZ[tid] = 1.0f / Z;
    ent = logf(Z) - lE[tid] / Z;
  }
  const float es = blockReduceSum256(ent, sbuf);
  if (tid == 0) atomicAdd(&scalars[1], es);
  __syncthreads();
  for (int sub = 0; sub < NCH; ++sub) {
    const int blin = rt * NCH + sub;
    const unsigned cnt = cbc[blin] < CAP_BLK ? cbc[blin] : CAP_BLK;
    const unsigned lim = (cnt + 255u) & ~255u;
    for (unsigned i = tid; i < lim; i += 256u) {
      bool nt = false;
      unsigned pr = 0u;
      if (i < cnt) {
        const unsigned long long e = cand[(size_t)blin * CAP_BLK + i];
        pr = (unsigned)(e & 0xFFFFFFFu);
        const float t = __uint_as_float((unsigned)(e >> 32));
        const int rowl = (int)((pr >> 14) & 63u);
        const float d = t - lM[rowl];
        atomicAdd(&colsum[pr & 0x3FFFu], exp2f(d * L2E100) * lIZ[rowl]);
        nt = (d >= -EPS_NT);
      }
      const unsigned long long mask = __ballot(nt);
      const unsigned cw = (unsigned)__popcll(mask);
      unsigned base = 0u;
      if (lane == 0 && cw) base = atomicAdd(ntc, cw);
      base = __shfl((int)base, 0);
      if (nt) {
        const unsigned off = (unsigned)__popcll(mask & ((1ull << lane) - 1ull));
        const unsigned s = base + off;
        if (s < NT_CAP) ntList[s] = pr;
      }
    }
  }
}

// ---------- fp64 re-rank of near-tie candidates (coalesced zT if available) ----------
__global__ __launch_bounds__(256) void k_refine(const float* __restrict__ z,
    const float* __restrict__ zT, const float* __restrict__ emb,
    const unsigned* __restrict__ ntList, const unsigned* __restrict__ ntc,
    unsigned long long* __restrict__ rowkey) {
  const unsigned cnt = *ntc;
  const unsigned lim = cnt < NT_CAP ? cnt : NT_CAP;
  const int lane = threadIdx.x & 63, wv = threadIdx.x >> 6;
  for (unsigned slot = blockIdx.x * 4 + wv; slot < lim; slot += gridDim.x * 4) {
    const unsigned pr = ntList[slot];
    const int n = (int)(pr >> 14), k = (int)(pr & 0x3FFFu);
    const int b = n >> 10, hw = n & 1023;
    double sz = 0.0, se = 0.0, sp = 0.0;
#pragma unroll
    for (int u = 0; u < CDIM / 64; ++u) {
      const int c = lane + u * 64;
      const double zv = (zT != nullptr)
          ? (double)zT[(size_t)n * CDIM + c]
          : (double)z[((size_t)(b * CDIM + c) << 10) + hw];
      const double ev = (double)emb[(size_t)k * CDIM + c];
      sz = fma(zv, zv, sz); se = fma(ev, ev, se); sp = fma(zv, ev, sp);
    }
    for (int off = 32; off; off >>= 1) {
      sz += __shfl_down(sz, off);
      se += __shfl_down(se, off);
      sp += __shfl_down(sp, off);
    }
    if (lane == 0) {
      const double nz = fmax(sqrt(sz), 1e-12);
      const double ne = fmax(sqrt(se), 1e-12);
      const double d = sz / (nz * nz) + se / (ne * ne) - 2.0 * sp / (nz * ne);
      const unsigned long long key =
          (((unsigned long long)(d * 140737488355328.0)) << 14) | (unsigned long long)k;
      atomicMin(&rowkey[n], key);
    }
  }
}

// ---------- z_q gather + idx extraction + vq sums ----------
__global__ __launch_bounds__(256) void k_zq(const unsigned short* __restrict__ A2,
    const unsigned short* __restrict__ B2, const unsigned long long* __restrict__ rowkey,
    const long long* __restrict__ qids, int* __restrict__ idxI,
    float* __restrict__ outIdxF, float* __restrict__ outZ,
    float* __restrict__ scalars) {
  __shared__ int lidx[64];
  __shared__ unsigned short tile[64 * 264];
  __shared__ float sbuf[4];
  const int b = blockIdx.x >> 4, hw0 = (blockIdx.x & 15) * 64;
  const int tid = threadIdx.x;
  if (tid < 64) {
    const int n = b * 1024 + hw0 + tid;
    const unsigned long long key = rowkey[n];
    const int k = (key != ~0ull) ? (int)(key & 0x3FFFull) : 0;
    lidx[tid] = k;
    idxI[n] = k;
    outIdxF[n] = (float)k;
  }
  __syncthreads();
  const long long qid = qids[b];
  const int rr = tid >> 5, tt = tid & 31;
  float vq = 0.f;
#pragma unroll
  for (int it = 0; it < 8; ++it) {
    const int row = rr + 8 * it;
    const int token = b * 1024 + hw0 + row;
    union { uint4 v; unsigned short s[8]; } ev, zv;
    ev.v = *(const uint4*)&B2[(size_t)lidx[row] * CDIM + tt * 8];
    zv.v = *(const uint4*)&A2[(size_t)token * CDIM + tt * 8];
    *(uint4*)&tile[row * 264 + tt * 8] = ev.v;
    float dd = 0.f;
#pragma unroll
    for (int u = 0; u < 8; ++u) {
      const float d = bf2f(ev.s[u]) - bf2f(zv.s[u]);
      dd = fmaf(d, d, dd);
    }
    if ((long long)(row & 31) <= qid) vq += dd;
  }
  const float s = blockReduceSum256(vq, sbuf);
  if (tid == 0) atomicAdd(&scalars[0], s * (1.0f / 256.0f));
  __syncthreads();
  const int cg = tid >> 6, hwl = tid & 63;
#pragma unroll 8
  for (int i = 0; i < 64; ++i) {
    const int c = cg + i * 4;
    outZ[((size_t)(b * CDIM + c) << 10) + hw0 + hwl] = bf2f(tile[hwl * 264 + c]);
  }
}

// ---------- final: avg-entropy from colsum + dead-code + scalar outputs ----------
__global__ __launch_bounds__(256) void k_final(const int* __restrict__ idxI,
    const long long* __restrict__ qids, const float* __restrict__ colsum,
    const float* __restrict__ scalars, float* __restrict__ out) {
  __shared__ float sbuf[4];
  const int tid = threadIdx.x;
  float ae = 0.f;
  for (int i = tid; i < N_E; i += 256) {
    const float q = colsum[i] * (1.0f / (float)N_TOK);
    ae += q * logf(q + 1e-5f);
  }
  const float aes = blockReduceSum256(ae, sbuf);   // = -avg_entropy
  int cnt = 0;
  for (int p = tid; p < 1024; p += 256) {
    const int v = idxI[p];
    bool eq = true;
    for (int b = 1; b < 16; ++b) eq = eq && (idxI[b * 1024 + p] == v);
    cnt += eq ? 1 : 0;
  }
  const float dc = blockReduceSum256((float)cnt, sbuf);
  if (tid == 0) {
    float denom = 0.f;
    for (int b = 0; b < 16; ++b) denom += (float)(qids[b] + 1ll);
    out[4194304] = scalars[0] / denom;
    out[4194305] = 0.25f * scalars[0] / denom;
    out[4194306] = 0.1f * (scalars[1] * (1.0f / (float)N_TOK) + aes);
    out[4194307] = dc * (1.0f / 1024.0f);
  }
}

extern "C" void kernel_launch(void* const* d_in, const int* in_sizes, int n_in,
                              void* d_out, int out_size, void* d_ws, size_t ws_size,
                              hipStream_t stream) {
  const float*      z    = (const float*)d_in[0];
  const float*      emb  = (const float*)d_in[1];
  const long long*  qids = (const long long*)d_in[2];
  float* out = (float*)d_out;
  float* W   = (float*)d_ws;

  unsigned short* A2 = (unsigned short*)(W + OFF_A2);
  unsigned short* B2 = (unsigned short*)(W + OFF_B2);
  unsigned* rowMaxU = (unsigned*)(W + OFF_RMX);
  float* colsum = W + OFF_CS;
  float* scal   = W + OFF_SC;
  unsigned long long* rowkey = (unsigned long long*)(W + OFF_RK);
  unsigned* ntList = (unsigned*)(W + OFF_NT);
  unsigned* ntc    = (unsigned*)(W + OFF_NTC);
  unsigned* cbc    = (unsigned*)(W + OFF_CBC);
  int* idxI        = (int*)(W + OFF_IDX);
  unsigned long long* cand = (unsigned long long*)(W + OFF_CAND);
  float* zT = (ws_size >= NEED_ZT_BYTES) ? (W + OFF_ZT) : (float*)nullptr;

  k_norm_emb<<<dim3(N_E / 4),     dim3(256), 0, stream>>>(emb, B2, colsum, scal,
                                                          rowkey, ntc, rowMaxU);
  k_norm_z  <<<dim3(256),         dim3(256), 0, stream>>>(z, A2, zT);
  k_pass1   <<<dim3(256, NCH),    dim3(256), 0, stream>>>(A2, B2, cand, cbc, rowMaxU);
  k_cstat2  <<<dim3(256),         dim3(256), 0, stream>>>(cand, cbc, rowMaxU, colsum,
                                                          ntList, ntc, scal);
  k_refine  <<<dim3(1024),        dim3(256), 0, stream>>>(z, zT, emb, ntList, ntc, rowkey);
  k_zq      <<<dim3(256),         dim3(256), 0, stream>>>(A2, B2, rowkey, qids,
                                                          idxI, out + 4194308, out, scal);
  k_final   <<<dim3(1),           dim3(256), 0, stream>>>(idxI, qids, colsum, scal, out);
}

// Round 4
// 654.781 us; speedup vs baseline: 1.4663x; 1.4663x over previous
//
#include <hip/hip_runtime.h>
#include <math.h>

// Problem constants
#define N_TOK   16384
#define N_E     16384
#define CDIM    256
#define NCH     8
#define CHSZ    (N_E / NCH)      // 2048 codes per chunk
#define L2E100  144.26950408889634f   // 100 * log2(e)
#define DELTA_C 0.06f            // candidate window below running row max
#define EPS_NT  0.008f           // near-tie window for fp64 argmin re-rank
#define CAP_BLK 1536u            // per-block candidate cap (proven r6-r14)
#define NT_CAP  65536u

typedef __attribute__((ext_vector_type(8))) short short8;
typedef __attribute__((ext_vector_type(4))) float f32x4;

// ---- workspace layout (float offsets); base 42.5 MB, zT optional tail ----
#define OFF_A2   0u          // ushort[16384*256] bf16-hi normalized z (token-major)
#define OFF_B2   2097152u    // ushort[16384*256] bf16-hi normalized emb
#define OFF_RMX  4194304u    // 16384 u32 ordered-key row max
#define OFF_CS   4210688u    // 16384 colsum
#define OFF_SC   4227072u    // 16 scalars
#define OFF_RK   4227088u    // 16384 u64 rowkey (8B aligned)
#define OFF_NT   4259856u    // 65536 u32 near-tie list
#define OFF_NTC  4325392u    // 16
#define OFF_CBC  4325408u    // 2048 per-block counts
#define OFF_IDX  4327456u    // 16384 int
#define OFF_CAND 4343840u    // u64[2048*1536] {f32 t | row<<14|col} (8B aligned)
#define OFF_ZT   10635296u   // float[16384*256] raw z token-major (refine coalescing)
#define NEED_ZT_BYTES 59318400ull

__device__ __forceinline__ unsigned short f2bf(float x) {
  unsigned u = __float_as_uint(x);
  unsigned r = (u + 0x7fffu + ((u >> 16) & 1u)) >> 16;
  return (unsigned short)r;
}
__device__ __forceinline__ float bf2f(unsigned short h) {
  return __uint_as_float(((unsigned)h) << 16);
}
__device__ __forceinline__ unsigned fkey(float f) {      // order-preserving float->uint
  unsigned u = __float_as_uint(f);
  return (u & 0x80000000u) ? ~u : (u | 0x80000000u);
}
__device__ __forceinline__ float keyf(unsigned k) {
  return (k & 0x80000000u) ? __uint_as_float(k ^ 0x80000000u) : __uint_as_float(~k);
}

__device__ __forceinline__ void async_load16(const void* g, void* l) {
  __builtin_amdgcn_global_load_lds((const __attribute__((address_space(1))) void*)g,
                                   (__attribute__((address_space(3))) void*)l, 16, 0, 0);
}

__device__ __forceinline__ float blockReduceSum256(float v, float* sbuf) {
  __syncthreads();
  v += __shfl_down(v, 32);
  v += __shfl_down(v, 16);
  v += __shfl_down(v, 8);
  v += __shfl_down(v, 4);
  v += __shfl_down(v, 2);
  v += __shfl_down(v, 1);
  const int tid = threadIdx.x;
  if ((tid & 63) == 0) sbuf[tid >> 6] = v;
  __syncthreads();
  return sbuf[0] + sbuf[1] + sbuf[2] + sbuf[3];
}

// ---------- emb normalize (wave-per-row) + fused workspace zeroing ----------
__global__ __launch_bounds__(256) void k_norm_emb(const float* __restrict__ emb,
    unsigned short* __restrict__ B2, float* __restrict__ colsum,
    float* __restrict__ scalars, unsigned long long* __restrict__ rowkey,
    unsigned* __restrict__ ntc, unsigned* __restrict__ rowMaxU) {
  const int tid = threadIdx.x, lane = tid & 63, wv = tid >> 6;
  if (blockIdx.x < 64) {
    const int i = blockIdx.x * 256 + tid;
    colsum[i] = 0.f;
    rowkey[i] = ~0ull;
    rowMaxU[i] = 0u;
    if (i < 16) { scalars[i] = 0.f; ntc[i] = 0u; }
  }
  const int k = blockIdx.x * 4 + wv;
  const float4 v = *(const float4*)&emb[(size_t)k * CDIM + lane * 4];
  float ss = v.x * v.x + v.y * v.y + v.z * v.z + v.w * v.w;
#pragma unroll
  for (int off = 1; off < 64; off <<= 1) ss += __shfl_xor(ss, off);
  const float r = 1.0f / fmaxf(sqrtf(ss), 1e-12f);
  ushort4 o;
  o.x = f2bf(v.x * r); o.y = f2bf(v.y * r);
  o.z = f2bf(v.z * r); o.w = f2bf(v.w * r);
  *(ushort4*)&B2[(size_t)k * CDIM + lane * 4] = o;
}

// ---------- coalesced z normalize + optional raw token-major copy ----------
__global__ __launch_bounds__(256) void k_norm_z(const float* __restrict__ z,
                                                unsigned short* __restrict__ A2,
                                                float* __restrict__ zT) {
  __shared__ float ssb[4][64];
  __shared__ float rn[64];
  __shared__ unsigned short tile[64 * 264];
  __shared__ float tileF[64 * 260];
  const int b = blockIdx.x >> 4, hw0 = (blockIdx.x & 15) * 64;
  const int tid = threadIdx.x, cg = tid >> 6, hwl = tid & 63;
  float ss = 0.f;
#pragma unroll 8
  for (int i = 0; i < 64; ++i) {
    const int c = cg + i * 4;
    const float x = z[((size_t)(b * CDIM + c) << 10) + hw0 + hwl];
    ss = fmaf(x, x, ss);
  }
  ssb[cg][hwl] = ss;
  __syncthreads();
  if (tid < 64) {
    const float t = ssb[0][tid] + ssb[1][tid] + ssb[2][tid] + ssb[3][tid];
    rn[tid] = 1.0f / fmaxf(sqrtf(t), 1e-12f);
  }
  __syncthreads();
  const float r = rn[hwl];
#pragma unroll 8
  for (int i = 0; i < 64; ++i) {
    const int c = cg + i * 4;
    const float x = z[((size_t)(b * CDIM + c) << 10) + hw0 + hwl];
    tile[hwl * 264 + c] = f2bf(x * r);
    tileF[hwl * 260 + c] = x;
  }
  __syncthreads();
  const int rr = tid >> 5, tt = tid & 31;
#pragma unroll
  for (int it = 0; it < 8; ++it) {
    const int row = rr + 8 * it;
    const int token = b * 1024 + hw0 + row;
    const uint4 v = *(const uint4*)&tile[row * 264 + tt * 8];
    *(uint4*)&A2[(size_t)token * CDIM + tt * 8] = v;
    if (zT != nullptr) {
      const float4 f0 = *(const float4*)&tileF[row * 260 + tt * 4];
      const float4 f1 = *(const float4*)&tileF[row * 260 + 128 + tt * 4];
      *(float4*)&zT[(size_t)token * CDIM + tt * 4] = f0;
      *(float4*)&zT[(size_t)token * CDIM + 128 + tt * 4] = f1;
    }
  }
}

// ============ pass 1: A in registers, B in a 3-deep LDS ring, counted vmcnt(4)
// (loads issued 2 phases ahead; no vmcnt(0) drain in the main loop; epilogue
// barrier is lgkmcnt-only). Single accumulator — no extra VGPR pressure. ============
__global__ __launch_bounds__(256, 3) void k_pass1(const unsigned short* __restrict__ A2,
    const unsigned short* __restrict__ B2,
    unsigned long long* __restrict__ cand, unsigned* __restrict__ cbc,
    unsigned* __restrict__ rowMaxU) {
  __shared__ alignas(16) unsigned short Bt[3][128 * 64];  // 3 x 16 KB B ring
  __shared__ unsigned smaxU[64];
  __shared__ unsigned lcnt;
  const int rt = blockIdx.x, chunk = blockIdx.y;   // swizzle: co-resident blocks share chunk
  const int r0 = rt * 64, k0 = chunk * CHSZ;
  const int blin = rt * NCH + chunk;
  const int tid = threadIdx.x, lane = tid & 63, w = tid >> 6;
  const int wrr = (w & 1) * 32, wc = (w >> 1) * 64;
  const int l15 = lane & 15, quad = lane >> 4;

  if (tid == 0) lcnt = 0u;
  if (tid < 64) smaxU[tid] = 0u;

  // A fragments -> registers (rows fixed per wave for whole kernel).
  short8 afr[2][4][2];
#pragma unroll
  for (int ti = 0; ti < 2; ++ti) {
    const size_t rbase = (size_t)(r0 + wrr + ti * 16 + l15) * CDIM;
#pragma unroll
    for (int st = 0; st < 4; ++st)
#pragma unroll
      for (int kk = 0; kk < 2; ++kk)
        afr[ti][st][kk] = *(const short8*)&A2[rbase + st * 64 + (((kk << 2) | quad) * 8)];
  }

  // per-thread B staging base (swizzle: position cg holds global group cg^(row&7));
  // the 4 per-thread loads stride +32 rows = +8192 ushorts globally / +4096 B in LDS.
  const int row0 = tid >> 3, cg0 = tid & 7;
  const int gcg0 = cg0 ^ (row0 & 7);
  const unsigned short* bsrc0 = B2 + (size_t)(k0 + row0) * CDIM + gcg0 * 8;
  const unsigned bofs0 = (unsigned)tid * 16u;

  // hoisted B LDS read offsets (buffer-relative; same for every ring slot)
  int boff[4][2];
#pragma unroll
  for (int tj = 0; tj < 4; ++tj) {
    const int br = wc + tj * 16 + l15;
#pragma unroll
    for (int kk = 0; kk < 2; ++kk)
      boff[tj][kk] = br * 64 + ((((kk << 2) | quad) ^ (br & 7)) * 8);
  }

  // prologue: stage phase 0 -> Bt[0], phase 1 -> Bt[1]
#pragma unroll
  for (int i = 0; i < 4; ++i)
    async_load16(bsrc0 + i * 8192, (char*)Bt[0] + bofs0 + i * 4096);
#pragma unroll
  for (int i = 0; i < 4; ++i)
    async_load16(bsrc0 + i * 8192 + 64, (char*)Bt[1] + bofs0 + i * 4096);
  // wait phase-0 data (leave phase-1's 4 loads in flight); drain own LDS init writes
  asm volatile("s_waitcnt vmcnt(4) lgkmcnt(0)" ::: "memory");
  __builtin_amdgcn_s_barrier();
  __builtin_amdgcn_sched_barrier(0);

  unsigned short* bufR = Bt[0];   // read this phase
  unsigned short* bufN = Bt[1];   // in flight for next phase
  unsigned short* bufW = Bt[2];   // write target (phase+2)

  f32x4 acc[2][4];
  size_t cb = 0;   // ct*32768 source advance (in ushorts)

#pragma unroll 1
  for (int ct = 0; ct < 16; ++ct) {
#pragma unroll
    for (int ti = 0; ti < 2; ++ti)
#pragma unroll
      for (int tj = 0; tj < 4; ++tj) acc[ti][tj] = (f32x4){0.f, 0.f, 0.f, 0.f};

#pragma unroll
    for (int st = 0; st < 4; ++st) {
      // prefetch phase q+2 into bufW (skip when q+2 > 63, i.e. ct15 st>=2)
      if (!(ct == 15 && st >= 2)) {
        const size_t noff = cb + ((st < 2) ? (size_t)((st + 2) * 64)
                                           : (size_t)(32768 + (st - 2) * 64));
#pragma unroll
        for (int i = 0; i < 4; ++i)
          async_load16(bsrc0 + noff + i * 8192, (char*)bufW + bofs0 + i * 4096);
      }

      // MFMA over current buffer
      __builtin_amdgcn_s_setprio(1);
#pragma unroll
      for (int kk = 0; kk < 2; ++kk) {
        short8 bfr[4];
#pragma unroll
        for (int tj = 0; tj < 4; ++tj)
          bfr[tj] = *(const short8*)&bufR[boff[tj][kk]];
#pragma unroll
        for (int ti = 0; ti < 2; ++ti)
#pragma unroll
          for (int tj = 0; tj < 4; ++tj)
            acc[ti][tj] = __builtin_amdgcn_mfma_f32_16x16x32_bf16(afr[ti][st][kk], bfr[tj],
                                                                  acc[ti][tj], 0, 0, 0);
      }
      __builtin_amdgcn_s_setprio(0);

      if (st == 3) {
        // ---- per-ct epilogue: t = 2*dot, row max, tight threshold, emit ----
        const int kb = k0 + ct * 128;
#pragma unroll
        for (int ti = 0; ti < 2; ++ti)
#pragma unroll
          for (int tj = 0; tj < 4; ++tj) {
            f32x4 a = acc[ti][tj];
#pragma unroll
            for (int r = 0; r < 4; ++r) a[r] = a[r] + a[r];   // t = 2*dot
            acc[ti][tj] = a;
          }
#pragma unroll
        for (int ti = 0; ti < 2; ++ti)
#pragma unroll
          for (int r = 0; r < 4; ++r) {
            float mt = fmaxf(fmaxf(acc[ti][0][r], acc[ti][1][r]),
                             fmaxf(acc[ti][2][r], acc[ti][3][r]));
            mt = fmaxf(mt, __shfl_xor(mt, 1));
            mt = fmaxf(mt, __shfl_xor(mt, 2));
            mt = fmaxf(mt, __shfl_xor(mt, 4));
            mt = fmaxf(mt, __shfl_xor(mt, 8));
            if (l15 == 0) atomicMax(&smaxU[wrr + ti * 16 + quad * 4 + r], fkey(mt));
          }
        // publish all waves' maxes: LDS-only barrier (no VMEM drain)
        asm volatile("s_waitcnt lgkmcnt(0)" ::: "memory");
        __builtin_amdgcn_s_barrier();
        __builtin_amdgcn_sched_barrier(0);
#pragma unroll
        for (int ti = 0; ti < 2; ++ti)
#pragma unroll
          for (int r = 0; r < 4; ++r) {
            const int rowloc = wrr + ti * 16 + quad * 4 + r;
            const float thr = keyf(smaxU[rowloc]) - DELTA_C;
            const unsigned rowg = (unsigned)(r0 + rowloc);
#pragma unroll
            for (int tj = 0; tj < 4; ++tj) {
              const float t = acc[ti][tj][r];
              if (t >= thr) {
                const unsigned slot = atomicAdd(&lcnt, 1u);
                if (slot < CAP_BLK) {
                  const unsigned pr = (rowg << 14) | (unsigned)(kb + wc + tj * 16 + l15);
                  cand[(size_t)blin * CAP_BLK + slot] =
                      ((unsigned long long)__float_as_uint(t) << 32) | pr;
                }
              }
            }
          }
      }

      // rotate ring; counted-vmcnt phase boundary (never drain to 0 mid-loop,
      // except the one point where no further prefetch was issued)
      {
        unsigned short* tmp = bufR; bufR = bufN; bufN = bufW; bufW = tmp;
      }
      if (ct == 15 && st == 2)
        asm volatile("s_waitcnt vmcnt(0)" ::: "memory");
      else
        asm volatile("s_waitcnt vmcnt(4)" ::: "memory");
      __builtin_amdgcn_s_barrier();
      __builtin_amdgcn_sched_barrier(0);
    }
    cb += 32768;
  }

  __syncthreads();   // full drain once: lcnt / smaxU / emissions stable
  if (tid < 64) atomicMax(&rowMaxU[r0 + tid], smaxU[tid]);
  if (tid == 0) cbc[blin] = lcnt < CAP_BLK ? lcnt : CAP_BLK;
}

// ---------- fused candidate processing: block = rt, LDS-local Z/E ----------
__global__ __launch_bounds__(256) void k_cstat2(const unsigned long long* __restrict__ cand,
    const unsigned* __restrict__ cbc, const unsigned* __restrict__ rowMaxU,
    float* __restrict__ colsum, unsigned* __restrict__ ntList,
    unsigned* __restrict__ ntc, float* __restrict__ scalars) {
  __shared__ float lM[64], lZ[64], lE[64], lIZ[64];
  __shared__ float sbuf[4];
  const int rt = blockIdx.x, r0 = rt * 64;
  const int tid = threadIdx.x, lane = tid & 63;
  if (tid < 64) {
    lM[tid] = keyf(rowMaxU[r0 + tid]);
    lZ[tid] = 0.f; lE[tid] = 0.f;
  }
  __syncthreads();
  for (int sub = 0; sub < NCH; ++sub) {
    const int blin = rt * NCH + sub;
    const unsigned cnt = cbc[blin] < CAP_BLK ? cbc[blin] : CAP_BLK;
    for (unsigned i = tid; i < cnt; i += 256u) {
      const unsigned long long e = cand[(size_t)blin * CAP_BLK + i];
      const unsigned pr = (unsigned)(e & 0xFFFFFFFu);
      const float t = __uint_as_float((unsigned)(e >> 32));
      const int rowl = (int)((pr >> 14) & 63u);
      const float d = t - lM[rowl];
      const float ex = exp2f(d * L2E100);
      atomicAdd(&lZ[rowl], ex);
      atomicAdd(&lE[rowl], d * 100.0f * ex);
    }
  }
  __syncthreads();
  float ent = 0.f;
  if (tid < 64) {
    const float Z = lZ[tid];
    lIZ[tid] = 1.0f / Z;
    ent = logf(Z) - lE[tid] / Z;
  }
  const float es = blockReduceSum256(ent, sbuf);
  if (tid == 0) atomicAdd(&scalars[1], es);
  __syncthreads();
  for (int sub = 0; sub < NCH; ++sub) {
    const int blin = rt * NCH + sub;
    const unsigned cnt = cbc[blin] < CAP_BLK ? cbc[blin] : CAP_BLK;
    const unsigned lim = (cnt + 255u) & ~255u;
    for (unsigned i = tid; i < lim; i += 256u) {
      bool nt = false;
      unsigned pr = 0u;
      if (i < cnt) {
        const unsigned long long e = cand[(size_t)blin * CAP_BLK + i];
        pr = (unsigned)(e & 0xFFFFFFFu);
        const float t = __uint_as_float((unsigned)(e >> 32));
        const int rowl = (int)((pr >> 14) & 63u);
        const float d = t - lM[rowl];
        atomicAdd(&colsum[pr & 0x3FFFu], exp2f(d * L2E100) * lIZ[rowl]);
        nt = (d >= -EPS_NT);
      }
      const unsigned long long mask = __ballot(nt);
      const unsigned cw = (unsigned)__popcll(mask);
      unsigned base = 0u;
      if (lane == 0 && cw) base = atomicAdd(ntc, cw);
      base = __shfl((int)base, 0);
      if (nt) {
        const unsigned off = (unsigned)__popcll(mask & ((1ull << lane) - 1ull));
        const unsigned s = base + off;
        if (s < NT_CAP) ntList[s] = pr;
      }
    }
  }
}

// ---------- fp64 re-rank of near-tie candidates (coalesced zT if available) ----------
__global__ __launch_bounds__(256) void k_refine(const float* __restrict__ z,
    const float* __restrict__ zT, const float* __restrict__ emb,
    const unsigned* __restrict__ ntList, const unsigned* __restrict__ ntc,
    unsigned long long* __restrict__ rowkey) {
  const unsigned cnt = *ntc;
  const unsigned lim = cnt < NT_CAP ? cnt : NT_CAP;
  const int lane = threadIdx.x & 63, wv = threadIdx.x >> 6;
  for (unsigned slot = blockIdx.x * 4 + wv; slot < lim; slot += gridDim.x * 4) {
    const unsigned pr = ntList[slot];
    const int n = (int)(pr >> 14), k = (int)(pr & 0x3FFFu);
    const int b = n >> 10, hw = n & 1023;
    double sz = 0.0, se = 0.0, sp = 0.0;
#pragma unroll
    for (int u = 0; u < CDIM / 64; ++u) {
      const int c = lane + u * 64;
      const double zv = (zT != nullptr)
          ? (double)zT[(size_t)n * CDIM + c]
          : (double)z[((size_t)(b * CDIM + c) << 10) + hw];
      const double ev = (double)emb[(size_t)k * CDIM + c];
      sz = fma(zv, zv, sz); se = fma(ev, ev, se); sp = fma(zv, ev, sp);
    }
    for (int off = 32; off; off >>= 1) {
      sz += __shfl_down(sz, off);
      se += __shfl_down(se, off);
      sp += __shfl_down(sp, off);
    }
    if (lane == 0) {
      const double nz = fmax(sqrt(sz), 1e-12);
      const double ne = fmax(sqrt(se), 1e-12);
      const double d = sz / (nz * nz) + se / (ne * ne) - 2.0 * sp / (nz * ne);
      const unsigned long long key =
          (((unsigned long long)(d * 140737488355328.0)) << 14) | (unsigned long long)k;
      atomicMin(&rowkey[n], key);
    }
  }
}

// ---------- z_q gather + idx extraction + vq sums ----------
__global__ __launch_bounds__(256) void k_zq(const unsigned short* __restrict__ A2,
    const unsigned short* __restrict__ B2, const unsigned long long* __restrict__ rowkey,
    const long long* __restrict__ qids, int* __restrict__ idxI,
    float* __restrict__ outIdxF, float* __restrict__ outZ,
    float* __restrict__ scalars) {
  __shared__ int lidx[64];
  __shared__ unsigned short tile[64 * 264];
  __shared__ float sbuf[4];
  const int b = blockIdx.x >> 4, hw0 = (blockIdx.x & 15) * 64;
  const int tid = threadIdx.x;
  if (tid < 64) {
    const int n = b * 1024 + hw0 + tid;
    const unsigned long long key = rowkey[n];
    const int k = (key != ~0ull) ? (int)(key & 0x3FFFull) : 0;
    lidx[tid] = k;
    idxI[n] = k;
    outIdxF[n] = (float)k;
  }
  __syncthreads();
  const long long qid = qids[b];
  const int rr = tid >> 5, tt = tid & 31;
  float vq = 0.f;
#pragma unroll
  for (int it = 0; it < 8; ++it) {
    const int row = rr + 8 * it;
    const int token = b * 1024 + hw0 + row;
    union { uint4 v; unsigned short s[8]; } ev, zv;
    ev.v = *(const uint4*)&B2[(size_t)lidx[row] * CDIM + tt * 8];
    zv.v = *(const uint4*)&A2[(size_t)token * CDIM + tt * 8];
    *(uint4*)&tile[row * 264 + tt * 8] = ev.v;
    float dd = 0.f;
#pragma unroll
    for (int u = 0; u < 8; ++u) {
      const float d = bf2f(ev.s[u]) - bf2f(zv.s[u]);
      dd = fmaf(d, d, dd);
    }
    if ((long long)(row & 31) <= qid) vq += dd;
  }
  const float s = blockReduceSum256(vq, sbuf);
  if (tid == 0) atomicAdd(&scalars[0], s * (1.0f / 256.0f));
  __syncthreads();
  const int cg = tid >> 6, hwl = tid & 63;
#pragma unroll 8
  for (int i = 0; i < 64; ++i) {
    const int c = cg + i * 4;
    outZ[((size_t)(b * CDIM + c) << 10) + hw0 + hwl] = bf2f(tile[hwl * 264 + c]);
  }
}

// ---------- final: avg-entropy from colsum + dead-code + scalar outputs ----------
__global__ __launch_bounds__(256) void k_final(const int* __restrict__ idxI,
    const long long* __restrict__ qids, const float* __restrict__ colsum,
    const float* __restrict__ scalars, float* __restrict__ out) {
  __shared__ float sbuf[4];
  const int tid = threadIdx.x;
  float ae = 0.f;
  for (int i = tid; i < N_E; i += 256) {
    const float q = colsum[i] * (1.0f / (float)N_TOK);
    ae += q * logf(q + 1e-5f);
  }
  const float aes = blockReduceSum256(ae, sbuf);   // = -avg_entropy
  int cnt = 0;
  for (int p = tid; p < 1024; p += 256) {
    const int v = idxI[p];
    bool eq = true;
    for (int b = 1; b < 16; ++b) eq = eq && (idxI[b * 1024 + p] == v);
    cnt += eq ? 1 : 0;
  }
  const float dc = blockReduceSum256((float)cnt, sbuf);
  if (tid == 0) {
    float denom = 0.f;
    for (int b = 0; b < 16; ++b) denom += (float)(qids[b] + 1ll);
    out[4194304] = scalars[0] / denom;
    out[4194305] = 0.25f * scalars[0] / denom;
    out[4194306] = 0.1f * (scalars[1] * (1.0f / (float)N_TOK) + aes);
    out[4194307] = dc * (1.0f / 1024.0f);
  }
}

extern "C" void kernel_launch(void* const* d_in, const int* in_sizes, int n_in,
                              void* d_out, int out_size, void* d_ws, size_t ws_size,
                              hipStream_t stream) {
  const float*      z    = (const float*)d_in[0];
  const float*      emb  = (const float*)d_in[1];
  const long long*  qids = (const long long*)d_in[2];
  float* out = (float*)d_out;
  float* W   = (float*)d_ws;

  unsigned short* A2 = (unsigned short*)(W + OFF_A2);
  unsigned short* B2 = (unsigned short*)(W + OFF_B2);
  unsigned* rowMaxU = (unsigned*)(W + OFF_RMX);
  float* colsum = W + OFF_CS;
  float* scal   = W + OFF_SC;
  unsigned long long* rowkey = (unsigned long long*)(W + OFF_RK);
  unsigned* ntList = (unsigned*)(W + OFF_NT);
  unsigned* ntc    = (unsigned*)(W + OFF_NTC);
  unsigned* cbc    = (unsigned*)(W + OFF_CBC);
  int* idxI        = (int*)(W + OFF_IDX);
  unsigned long long* cand = (unsigned long long*)(W + OFF_CAND);
  float* zT = (ws_size >= NEED_ZT_BYTES) ? (W + OFF_ZT) : (float*)nullptr;

  k_norm_emb<<<dim3(N_E / 4),     dim3(256), 0, stream>>>(emb, B2, colsum, scal,
                                                          rowkey, ntc, rowMaxU);
  k_norm_z  <<<dim3(256),         dim3(256), 0, stream>>>(z, A2, zT);
  k_pass1   <<<dim3(256, NCH),    dim3(256), 0, stream>>>(A2, B2, cand, cbc, rowMaxU);
  k_cstat2  <<<dim3(256),         dim3(256), 0, stream>>>(cand, cbc, rowMaxU, colsum,
                                                          ntList, ntc, scal);
  k_refine  <<<dim3(1024),        dim3(256), 0, stream>>>(z, zT, emb, ntList, ntc, rowkey);
  k_zq      <<<dim3(256),         dim3(256), 0, stream>>>(A2, B2, rowkey, qids,
                                                          idxI, out + 4194308, out, scal);
  k_final   <<<dim3(1),           dim3(256), 0, stream>>>(idxI, qids, colsum, scal, out);
}

// Round 7
// 548.541 us; speedup vs baseline: 1.7503x; 1.1937x over previous
//
#include <hip/hip_runtime.h>
#include <math.h>

// Problem constants
#define N_TOK   16384
#define N_E     16384
#define CDIM    256
#define NCH     8
#define CHSZ    (N_E / NCH)      // 2048 codes per chunk
#define L2E100  144.26950408889634f   // 100 * log2(e)
#define DELTA_C 0.06f            // candidate window below running row max (t-units)
#define DELTA_D 0.03f            // same window in dot-units (t = 2*dot)
#define EPS_NT  0.008f           // near-tie window for fp64 argmin re-rank
#define CAP_BLK 1536u            // per-block candidate cap (proven r6-r14)
#define NT_CAP  65536u

typedef __attribute__((ext_vector_type(8))) short short8;
typedef __attribute__((ext_vector_type(4))) float f32x4;

// ---- workspace layout (float offsets); base 42.5 MB, zT optional tail ----
#define OFF_A2   0u          // ushort[16384*256] bf16-hi normalized z (token-major)
#define OFF_B2   2097152u    // ushort[16384*256] bf16-hi normalized emb
#define OFF_RMX  4194304u    // 16384 u32 ordered-key row max
#define OFF_CS   4210688u    // 16384 colsum
#define OFF_SC   4227072u    // 16 scalars
#define OFF_RK   4227088u    // 16384 u64 rowkey (8B aligned)
#define OFF_NT   4259856u    // 65536 u32 near-tie list
#define OFF_NTC  4325392u    // 16
#define OFF_CBC  4325408u    // 2048 per-block counts
#define OFF_IDX  4327456u    // 16384 int
#define OFF_CAND 4343840u    // u64[2048*1536] {f32 t | row<<14|col} (8B aligned)
#define OFF_ZT   10635296u   // float[16384*256] raw z token-major (refine coalescing)
#define NEED_ZT_BYTES 59318400ull

__device__ __forceinline__ unsigned short f2bf(float x) {
  unsigned u = __float_as_uint(x);
  unsigned r = (u + 0x7fffu + ((u >> 16) & 1u)) >> 16;
  return (unsigned short)r;
}
__device__ __forceinline__ float bf2f(unsigned short h) {
  return __uint_as_float(((unsigned)h) << 16);
}
__device__ __forceinline__ unsigned fkey(float f) {      // order-preserving float->uint
  unsigned u = __float_as_uint(f);
  return (u & 0x80000000u) ? ~u : (u | 0x80000000u);
}
__device__ __forceinline__ float keyf(unsigned k) {
  return (k & 0x80000000u) ? __uint_as_float(k ^ 0x80000000u) : __uint_as_float(~k);
}

__device__ __forceinline__ void async_load16(const void* g, void* l) {
  __builtin_amdgcn_global_load_lds((const __attribute__((address_space(1))) void*)g,
                                   (__attribute__((address_space(3))) void*)l, 16, 0, 0);
}

__device__ __forceinline__ float blockReduceSum256(float v, float* sbuf) {
  __syncthreads();
  v += __shfl_down(v, 32);
  v += __shfl_down(v, 16);
  v += __shfl_down(v, 8);
  v += __shfl_down(v, 4);
  v += __shfl_down(v, 2);
  v += __shfl_down(v, 1);
  const int tid = threadIdx.x;
  if ((tid & 63) == 0) sbuf[tid >> 6] = v;
  __syncthreads();
  return sbuf[0] + sbuf[1] + sbuf[2] + sbuf[3];
}

// ---------- emb normalize (wave-per-row) + fused workspace zeroing ----------
__global__ __launch_bounds__(256) void k_norm_emb(const float* __restrict__ emb,
    unsigned short* __restrict__ B2, float* __restrict__ colsum,
    float* __restrict__ scalars, unsigned long long* __restrict__ rowkey,
    unsigned* __restrict__ ntc, unsigned* __restrict__ rowMaxU) {
  const int tid = threadIdx.x, lane = tid & 63, wv = tid >> 6;
  if (blockIdx.x < 64) {
    const int i = blockIdx.x * 256 + tid;
    colsum[i] = 0.f;
    rowkey[i] = ~0ull;
    rowMaxU[i] = 0u;
    if (i < 16) { scalars[i] = 0.f; ntc[i] = 0u; }
  }
  const int k = blockIdx.x * 4 + wv;
  const float4 v = *(const float4*)&emb[(size_t)k * CDIM + lane * 4];
  float ss = v.x * v.x + v.y * v.y + v.z * v.z + v.w * v.w;
#pragma unroll
  for (int off = 1; off < 64; off <<= 1) ss += __shfl_xor(ss, off);
  const float r = 1.0f / fmaxf(sqrtf(ss), 1e-12f);
  ushort4 o;
  o.x = f2bf(v.x * r); o.y = f2bf(v.y * r);
  o.z = f2bf(v.z * r); o.w = f2bf(v.w * r);
  *(ushort4*)&B2[(size_t)k * CDIM + lane * 4] = o;
}

// ---------- coalesced z normalize + optional raw token-major copy ----------
__global__ __launch_bounds__(256) void k_norm_z(const float* __restrict__ z,
                                                unsigned short* __restrict__ A2,
                                                float* __restrict__ zT) {
  __shared__ float ssb[4][64];
  __shared__ float rn[64];
  __shared__ unsigned short tile[64 * 264];
  __shared__ float tileF[64 * 260];
  const int b = blockIdx.x >> 4, hw0 = (blockIdx.x & 15) * 64;
  const int tid = threadIdx.x, cg = tid >> 6, hwl = tid & 63;
  float ss = 0.f;
#pragma unroll 8
  for (int i = 0; i < 64; ++i) {
    const int c = cg + i * 4;
    const float x = z[((size_t)(b * CDIM + c) << 10) + hw0 + hwl];
    ss = fmaf(x, x, ss);
  }
  ssb[cg][hwl] = ss;
  __syncthreads();
  if (tid < 64) {
    const float t = ssb[0][tid] + ssb[1][tid] + ssb[2][tid] + ssb[3][tid];
    rn[tid] = 1.0f / fmaxf(sqrtf(t), 1e-12f);
  }
  __syncthreads();
  const float r = rn[hwl];
#pragma unroll 8
  for (int i = 0; i < 64; ++i) {
    const int c = cg + i * 4;
    const float x = z[((size_t)(b * CDIM + c) << 10) + hw0 + hwl];
    tile[hwl * 264 + c] = f2bf(x * r);
    tileF[hwl * 260 + c] = x;
  }
  __syncthreads();
  const int rr = tid >> 5, tt = tid & 31;
#pragma unroll
  for (int it = 0; it < 8; ++it) {
    const int row = rr + 8 * it;
    const int token = b * 1024 + hw0 + row;
    const uint4 v = *(const uint4*)&tile[row * 264 + tt * 8];
    *(uint4*)&A2[(size_t)token * CDIM + tt * 8] = v;
    if (zT != nullptr) {
      const float4 f0 = *(const float4*)&tileF[row * 260 + tt * 4];
      const float4 f1 = *(const float4*)&tileF[row * 260 + 128 + tt * 4];
      *(float4*)&zT[(size_t)token * CDIM + tt * 4] = f0;
      *(float4*)&zT[(size_t)token * CDIM + 128 + tt * 4] = f1;
    }
  }
}

// ============ pass 1: wave-local epilogue. Each wave owns 16 token-rows x all
// 128 codes of the ct => per-row running max lives in registers; no smaxU LDS
// exchange, no epilogue barrier, no LDS atomics. Staging identical to the
// 328us baseline (2-buf dbuf + __syncthreads per phase). ============
__global__ __launch_bounds__(256, 3) void k_pass1(const unsigned short* __restrict__ A2,
    const unsigned short* __restrict__ B2,
    unsigned long long* __restrict__ cand, unsigned* __restrict__ cbc,
    unsigned* __restrict__ rowMaxU) {
  __shared__ alignas(16) unsigned short Bt[2][128 * 64];  // 2 x 16 KB B dbuf
  __shared__ unsigned lcnt;
  const int rt = blockIdx.x, chunk = blockIdx.y;   // swizzle: co-resident blocks share chunk
  const int r0 = rt * 64, k0 = chunk * CHSZ;
  const int blin = rt * NCH + chunk;
  const int tid = threadIdx.x, lane = tid & 63, w = tid >> 6;
  const int wr0 = w * 16;                // wave owns rows wr0..wr0+15, cols 0..127
  const int l15 = lane & 15, quad = lane >> 4;

  if (tid == 0) lcnt = 0u;

  // A fragments -> registers (16 rows per wave, fixed for whole kernel).
  short8 afr[4][2];
  {
    const size_t rbase = (size_t)(r0 + wr0 + l15) * CDIM;
#pragma unroll
    for (int st = 0; st < 4; ++st)
#pragma unroll
      for (int kk = 0; kk < 2; ++kk)
        afr[st][kk] = *(const short8*)&A2[rbase + st * 64 + (((kk << 2) | quad) * 8)];
  }

  // per-thread B staging base (swizzle: position cg holds global group cg^(row&7));
  // 4 per-thread loads stride +32 rows = +8192 ushorts globally / +4096 B in LDS.
  const int row0 = tid >> 3, cg0 = tid & 7;
  const int gcg0 = cg0 ^ (row0 & 7);
  const unsigned short* bsrc0 = B2 + (size_t)(k0 + row0) * CDIM + gcg0 * 8;
  const unsigned bofs0 = (unsigned)tid * 16u;

  // hoisted B LDS read offsets: 8 tj fragments (all 128 codes), 2 kk halves
  int boff[8][2];
#pragma unroll
  for (int tj = 0; tj < 8; ++tj) {
    const int br = tj * 16 + l15;
#pragma unroll
    for (int kk = 0; kk < 2; ++kk)
      boff[tj][kk] = br * 64 + ((((kk << 2) | quad) ^ (br & 7)) * 8);
  }

  // prologue: stage ct0-st0 into Bt[0]
#pragma unroll
  for (int i = 0; i < 4; ++i)
    async_load16(bsrc0 + i * 8192, (char*)Bt[0] + bofs0 + i * 4096);
  __syncthreads();

  f32x4 acc[8];
  float runMax[4];
#pragma unroll
  for (int r = 0; r < 4; ++r) runMax[r] = -3.0e38f;

#pragma unroll 1
  for (int ct = 0; ct < 16; ++ct) {
#pragma unroll
    for (int tj = 0; tj < 8; ++tj) acc[tj] = (f32x4){0.f, 0.f, 0.f, 0.f};

#pragma unroll
    for (int st = 0; st < 4; ++st) {
      // prefetch next phase into the other buffer
      if (!(ct == 15 && st == 3)) {
        const int noff = (st < 3) ? (st + 1) * 64 : 32768;
        char* dbuf = (char*)Bt[(st + 1) & 1];
#pragma unroll
        for (int i = 0; i < 4; ++i)
          async_load16(bsrc0 + noff + i * 8192, dbuf + bofs0 + i * 4096);
      }
      const unsigned short* bp = Bt[st & 1];
#pragma unroll
      for (int kk = 0; kk < 2; ++kk) {
        short8 bfr[8];
#pragma unroll
        for (int tj = 0; tj < 8; ++tj)
          bfr[tj] = *(const short8*)&bp[boff[tj][kk]];
#pragma unroll
        for (int tj = 0; tj < 8; ++tj)
          acc[tj] = __builtin_amdgcn_mfma_f32_16x16x32_bf16(afr[st][kk], bfr[tj],
                                                            acc[tj], 0, 0, 0);
      }

      if (st == 3) {
        // ---- wave-local epilogue (dot-units; t = 2*dot emitted) ----
        const int kb = k0 + ct * 128;
#pragma unroll
        for (int r = 0; r < 4; ++r) {
          float mt = acc[0][r];
#pragma unroll
          for (int tj = 1; tj < 8; ++tj) mt = fmaxf(mt, acc[tj][r]);
          mt = fmaxf(mt, __shfl_xor(mt, 1));
          mt = fmaxf(mt, __shfl_xor(mt, 2));
          mt = fmaxf(mt, __shfl_xor(mt, 4));
          mt = fmaxf(mt, __shfl_xor(mt, 8));
          runMax[r] = fmaxf(runMax[r], mt);
          const float thrD = runMax[r] - DELTA_D;
          const unsigned rowg = (unsigned)(r0 + wr0 + quad * 4 + r);
#pragma unroll
          for (int tj = 0; tj < 8; ++tj) {
            const float d = acc[tj][r];
            if (d >= thrD) {
              const unsigned slot = atomicAdd(&lcnt, 1u);
              if (slot < CAP_BLK) {
                const float t = d + d;
                const unsigned pr = (rowg << 14) | (unsigned)(kb + tj * 16 + l15);
                cand[(size_t)blin * CAP_BLK + slot] =
                    ((unsigned long long)__float_as_uint(t) << 32) | pr;
              }
            }
          }
        }
      }
      __syncthreads();
    }
    bsrc0 += 32768;
  }

  // merge per-wave running row maxima to global (t-units = 2*dot)
#pragma unroll
  for (int r = 0; r < 4; ++r)
    if (l15 == 0)
      atomicMax(&rowMaxU[r0 + wr0 + quad * 4 + r], fkey(runMax[r] + runMax[r]));
  if (tid == 0) cbc[blin] = lcnt < CAP_BLK ? lcnt : CAP_BLK;
}

// ---------- fused candidate processing: block = rt, LDS-local Z/E ----------
__global__ __launch_bounds__(256) void k_cstat2(const unsigned long long* __restrict__ cand,
    const unsigned* __restrict__ cbc, const unsigned* __restrict__ rowMaxU,
    float* __restrict__ colsum, unsigned* __restrict__ ntList,
    unsigned* __restrict__ ntc, float* __restrict__ scalars) {
  __shared__ float lM[64], lZ[64], lE[64], lIZ[64];
  __shared__ float sbuf[4];
  const int rt = blockIdx.x, r0 = rt * 64;
  const int tid = threadIdx.x, lane = tid & 63;
  if (tid < 64) {
    lM[tid] = keyf(rowMaxU[r0 + tid]);
    lZ[tid] = 0.f; lE[tid] = 0.f;
  }
  __syncthreads();
  for (int sub = 0; sub < NCH; ++sub) {
    const int blin = rt * NCH + sub;
    const unsigned cnt = cbc[blin] < CAP_BLK ? cbc[blin] : CAP_BLK;
    for (unsigned i = tid; i < cnt; i += 256u) {
      const unsigned long long e = cand[(size_t)blin * CAP_BLK + i];
      const unsigned pr = (unsigned)(e & 0xFFFFFFFu);
      const float t = __uint_as_float((unsigned)(e >> 32));
      const int rowl = (int)((pr >> 14) & 63u);
      const float d = t - lM[rowl];
      const float ex = exp2f(d * L2E100);
      atomicAdd(&lZ[rowl], ex);
      atomicAdd(&lE[rowl], d * 100.0f * ex);
    }
  }
  __syncthreads();
  float ent = 0.f;
  if (tid < 64) {
    const float Z = lZ[tid];
    lIZ[tid] = 1.0f / Z;
    ent = logf(Z) - lE[tid] / Z;
  }
  const float es = blockReduceSum256(ent, sbuf);
  if (tid == 0) atomicAdd(&scalars[1], es);
  __syncthreads();
  for (int sub = 0; sub < NCH; ++sub) {
    const int blin = rt * NCH + sub;
    const unsigned cnt = cbc[blin] < CAP_BLK ? cbc[blin] : CAP_BLK;
    const unsigned lim = (cnt + 255u) & ~255u;
    for (unsigned i = tid; i < lim; i += 256u) {
      bool nt = false;
      unsigned pr = 0u;
      if (i < cnt) {
        const unsigned long long e = cand[(size_t)blin * CAP_BLK + i];
        pr = (unsigned)(e & 0xFFFFFFFu);
        const float t = __uint_as_float((unsigned)(e >> 32));
        const int rowl = (int)((pr >> 14) & 63u);
        const float d = t - lM[rowl];
        atomicAdd(&colsum[pr & 0x3FFFu], exp2f(d * L2E100) * lIZ[rowl]);
        nt = (d >= -EPS_NT);
      }
      const unsigned long long mask = __ballot(nt);
      const unsigned cw = (unsigned)__popcll(mask);
      unsigned base = 0u;
      if (lane == 0 && cw) base = atomicAdd(ntc, cw);
      base = __shfl((int)base, 0);
      if (nt) {
        const unsigned off = (unsigned)__popcll(mask & ((1ull << lane) - 1ull));
        const unsigned s = base + off;
        if (s < NT_CAP) ntList[s] = pr;
      }
    }
  }
}

// ---------- fp64 re-rank of near-tie candidates (coalesced zT if available) ----------
__global__ __launch_bounds__(256) void k_refine(const float* __restrict__ z,
    const float* __restrict__ zT, const float* __restrict__ emb,
    const unsigned* __restrict__ ntList, const unsigned* __restrict__ ntc,
    unsigned long long* __restrict__ rowkey) {
  const unsigned cnt = *ntc;
  const unsigned lim = cnt < NT_CAP ? cnt : NT_CAP;
  const int lane = threadIdx.x & 63, wv = threadIdx.x >> 6;
  for (unsigned slot = blockIdx.x * 4 + wv; slot < lim; slot += gridDim.x * 4) {
    const unsigned pr = ntList[slot];
    const int n = (int)(pr >> 14), k = (int)(pr & 0x3FFFu);
    const int b = n >> 10, hw = n & 1023;
    double sz = 0.0, se = 0.0, sp = 0.0;
#pragma unroll
    for (int u = 0; u < CDIM / 64; ++u) {
      const int c = lane + u * 64;
      const double zv = (zT != nullptr)
          ? (double)zT[(size_t)n * CDIM + c]
          : (double)z[((size_t)(b * CDIM + c) << 10) + hw];
      const double ev = (double)emb[(size_t)k * CDIM + c];
      sz = fma(zv, zv, sz); se = fma(ev, ev, se); sp = fma(zv, ev, sp);
    }
    for (int off = 32; off; off >>= 1) {
      sz += __shfl_down(sz, off);
      se += __shfl_down(se, off);
      sp += __shfl_down(sp, off);
    }
    if (lane == 0) {
      const double nz = fmax(sqrt(sz), 1e-12);
      const double ne = fmax(sqrt(se), 1e-12);
      const double d = sz / (nz * nz) + se / (ne * ne) - 2.0 * sp / (nz * ne);
      const unsigned long long key =
          (((unsigned long long)(d * 140737488355328.0)) << 14) | (unsigned long long)k;
      atomicMin(&rowkey[n], key);
    }
  }
}

// ---------- z_q gather + idx extraction + vq sums ----------
__global__ __launch_bounds__(256) void k_zq(const unsigned short* __restrict__ A2,
    const unsigned short* __restrict__ B2, const unsigned long long* __restrict__ rowkey,
    const long long* __restrict__ qids, int* __restrict__ idxI,
    float* __restrict__ outIdxF, float* __restrict__ outZ,
    float* __restrict__ scalars) {
  __shared__ int lidx[64];
  __shared__ unsigned short tile[64 * 264];
  __shared__ float sbuf[4];
  const int b = blockIdx.x >> 4, hw0 = (blockIdx.x & 15) * 64;
  const int tid = threadIdx.x;
  if (tid < 64) {
    const int n = b * 1024 + hw0 + tid;
    const unsigned long long key = rowkey[n];
    const int k = (key != ~0ull) ? (int)(key & 0x3FFFull) : 0;
    lidx[tid] = k;
    idxI[n] = k;
    outIdxF[n] = (float)k;
  }
  __syncthreads();
  const long long qid = qids[b];
  const int rr = tid >> 5, tt = tid & 31;
  float vq = 0.f;
#pragma unroll
  for (int it = 0; it < 8; ++it) {
    const int row = rr + 8 * it;
    const int token = b * 1024 + hw0 + row;
    union { uint4 v; unsigned short s[8]; } ev, zv;
    ev.v = *(const uint4*)&B2[(size_t)lidx[row] * CDIM + tt * 8];
    zv.v = *(const uint4*)&A2[(size_t)token * CDIM + tt * 8];
    *(uint4*)&tile[row * 264 + tt * 8] = ev.v;
    float dd = 0.f;
#pragma unroll
    for (int u = 0; u < 8; ++u) {
      const float d = bf2f(ev.s[u]) - bf2f(zv.s[u]);
      dd = fmaf(d, d, dd);
    }
    if ((long long)(row & 31) <= qid) vq += dd;
  }
  const float s = blockReduceSum256(vq, sbuf);
  if (tid == 0) atomicAdd(&scalars[0], s * (1.0f / 256.0f));
  __syncthreads();
  const int cg = tid >> 6, hwl = tid & 63;
#pragma unroll 8
  for (int i = 0; i < 64; ++i) {
    const int c = cg + i * 4;
    outZ[((size_t)(b * CDIM + c) << 10) + hw0 + hwl] = bf2f(tile[hwl * 264 + c]);
  }
}

// ---------- final: avg-entropy from colsum + dead-code + scalar outputs ----------
__global__ __launch_bounds__(256) void k_final(const int* __restrict__ idxI,
    const long long* __restrict__ qids, const float* __restrict__ colsum,
    const float* __restrict__ scalars, float* __restrict__ out) {
  __shared__ float sbuf[4];
  const int tid = threadIdx.x;
  float ae = 0.f;
  for (int i = tid; i < N_E; i += 256) {
    const float q = colsum[i] * (1.0f / (float)N_TOK);
    ae += q * logf(q + 1e-5f);
  }
  const float aes = blockReduceSum256(ae, sbuf);   // = -avg_entropy
  int cnt = 0;
  for (int p = tid; p < 1024; p += 256) {
    const int v = idxI[p];
    bool eq = true;
    for (int b = 1; b < 16; ++b) eq = eq && (idxI[b * 1024 + p] == v);
    cnt += eq ? 1 : 0;
  }
  const float dc = blockReduceSum256((float)cnt, sbuf);
  if (tid == 0) {
    float denom = 0.f;
    for (int b = 0; b < 16; ++b) denom += (float)(qids[b] + 1ll);
    out[4194304] = scalars[0] / denom;
    out[4194305] = 0.25f * scalars[0] / denom;
    out[4194306] = 0.1f * (scalars[1] * (1.0f / (float)N_TOK) + aes);
    out[4194307] = dc * (1.0f / 1024.0f);
  }
}

extern "C" void kernel_launch(void* const* d_in, const int* in_sizes, int n_in,
                              void* d_out, int out_size, void* d_ws, size_t ws_size,
                              hipStream_t stream) {
  const float*      z    = (const float*)d_in[0];
  const float*      emb  = (const float*)d_in[1];
  const long long*  qids = (const long long*)d_in[2];
  float* out = (float*)d_out;
  float* W   = (float*)d_ws;

  unsigned short* A2 = (unsigned short*)(W + OFF_A2);
  unsigned short* B2 = (unsigned short*)(W + OFF_B2);
  unsigned* rowMaxU = (unsigned*)(W + OFF_RMX);
  float* colsum = W + OFF_CS;
  float* scal   = W + OFF_SC;
  unsigned long long* rowkey = (unsigned long long*)(W + OFF_RK);
  unsigned* ntList = (unsigned*)(W + OFF_NT);
  unsigned* ntc    = (unsigned*)(W + OFF_NTC);
  unsigned* cbc    = (unsigned*)(W + OFF_CBC);
  int* idxI        = (int*)(W + OFF_IDX);
  unsigned long long* cand = (unsigned long long*)(W + OFF_CAND);
  float* zT = (ws_size >= NEED_ZT_BYTES) ? (W + OFF_ZT) : (float*)nullptr;

  k_norm_emb<<<dim3(N_E / 4),     dim3(256), 0, stream>>>(emb, B2, colsum, scal,
                                                          rowkey, ntc, rowMaxU);
  k_norm_z  <<<dim3(256),         dim3(256), 0, stream>>>(z, A2, zT);
  k_pass1   <<<dim3(256, NCH),    dim3(256), 0, stream>>>(A2, B2, cand, cbc, rowMaxU);
  k_cstat2  <<<dim3(256),         dim3(256), 0, stream>>>(cand, cbc, rowMaxU, colsum,
                                                          ntList, ntc, scal);
  k_refine  <<<dim3(1024),        dim3(256), 0, stream>>>(z, zT, emb, ntList, ntc, rowkey);
  k_zq      <<<dim3(256),         dim3(256), 0, stream>>>(A2, B2, rowkey, qids,
                                                          idxI, out + 4194308, out, scal);
  k_final   <<<dim3(1),           dim3(256), 0, stream>>>(idxI, qids, colsum, scal, out);
}